// Round 9
// baseline (836.677 us; speedup 1.0000x reference)
//
#include <hip/hip_runtime.h>

#define S_LEN 2048
#define E_DIM 1024
#define NH 16
#define HD 128
#define NB 2
#define NPAIR (NH*NB)

typedef __attribute__((ext_vector_type(4))) float f32x4;
typedef __attribute__((ext_vector_type(8))) short bf16x8;

__device__ __forceinline__ unsigned short f2bf(float f) {
    unsigned u = __builtin_bit_cast(unsigned, f);
    u += 0x7fffu + ((u >> 16) & 1u);
    return (unsigned short)(u >> 16);
}
// packed f32x2 -> bf16x2 (RTNE), one VALU inst
__device__ __forceinline__ unsigned cvtpk(float lo, float hi) {
    unsigned r;
    asm("v_cvt_pk_bf16_f32 %0, %1, %2" : "=v"(r) : "v"(lo), "v"(hi));
    return r;
}

__device__ __forceinline__ void gl_lds16(const unsigned short* g, unsigned short* l) {
    __builtin_amdgcn_global_load_lds((__attribute__((address_space(1))) void*)g,
                                     (__attribute__((address_space(3))) void*)l,
                                     16, 0, 0);
}

// C[M,N] = A[M,K] @ B[N,K]^T (+bias_row +bias_col), bf16 in, fp32 acc.
// 2-phase double-buffered. SWZ=1: XCD-chunked swizzle (needs nwg%8==0).
template<int OF32, int SWZ>
__global__ __launch_bounds__(256, 2) void gemm_bt(
    const unsigned short* __restrict__ A, const unsigned short* __restrict__ B,
    void* __restrict__ C,
    const float* __restrict__ brow, const float* __restrict__ bcol,
    int K, int lda, int ldb, int ldc, int zdiv,
    long long a_sh, long long a_sl, long long b_sh, long long b_sl,
    long long c_sh, long long c_sl, int brs, int bcs)
{
    __shared__ unsigned short As[2][128*64];
    __shared__ unsigned short Bs[2][128*64];
    int bm, bn, z;
    if (SWZ) {
        const int gx = gridDim.x, gy = gridDim.y;
        const int nxy = gx * gy;
        const int nwg = nxy * gridDim.z;
        const int flat = (blockIdx.z*gy + blockIdx.y)*gx + blockIdx.x;
        const int id2 = (flat & 7)*(nwg >> 3) + (flat >> 3);
        z = id2 / nxy; const int r = id2 % nxy; bm = r / gx; bn = r % gx;
    } else { bm = blockIdx.y; bn = blockIdx.x; z = blockIdx.z; }
    const int zh = z / zdiv, zl = z % zdiv;
    A += (long long)zh*a_sh + (long long)zl*a_sl;
    B += (long long)zh*b_sh + (long long)zl*b_sl;
    const long long coff = (long long)zh*c_sh + (long long)zl*c_sl;
    const int tid = threadIdx.x, wid = tid >> 6, lane = tid & 63;
    const int l3 = lane >> 3;
    const int cg = (lane & 7) ^ l3;
    const unsigned short* Ag = A + (long long)(bm*128 + wid*32 + l3)*lda + cg*8;
    const unsigned short* Bg = B + (long long)(bn*128 + wid*32 + l3)*ldb + cg*8;

    f32x4 acc[4][4];
    #pragma unroll
    for (int m = 0; m < 4; ++m)
        #pragma unroll
        for (int n = 0; n < 4; ++n)
            #pragma unroll
            for (int j = 0; j < 4; ++j) acc[m][n][j] = 0.f;

    const int r0 = lane & 15, q = lane >> 4;
    const int wr = (wid >> 1) * 64, wc = (wid & 1) * 64;

    auto stage = [&](int buf, int kt) {
        unsigned short* as = &As[buf][wid*32*64];
        unsigned short* bs = &Bs[buf][wid*32*64];
        #pragma unroll
        for (int i = 0; i < 4; ++i) {
            gl_lds16(Ag + (long long)(i*8)*lda + kt, as + i*8*64);
            gl_lds16(Bg + (long long)(i*8)*ldb + kt, bs + i*8*64);
        }
    };

    const int nt = K >> 6;
    stage(0, 0);
    __syncthreads();
    int cur = 0;
    for (int t = 0; t < nt; ++t) {
        if (t + 1 < nt) stage(cur ^ 1, (t + 1) << 6);
        #pragma unroll
        for (int ks = 0; ks < 2; ++ks) {
            bf16x8 av[4], bv[4];
            #pragma unroll
            for (int m = 0; m < 4; ++m) {
                const int ra = wr + m*16 + r0;
                av[m] = *(const bf16x8*)&As[cur][ra*64 + (((ks*4 + q) ^ (ra & 7)) << 3)];
                const int rb = wc + m*16 + r0;
                bv[m] = *(const bf16x8*)&Bs[cur][rb*64 + (((ks*4 + q) ^ (rb & 7)) << 3)];
            }
            __builtin_amdgcn_s_setprio(1);
            #pragma unroll
            for (int m = 0; m < 4; ++m)
                #pragma unroll
                for (int n = 0; n < 4; ++n)
                    acc[m][n] = __builtin_amdgcn_mfma_f32_16x16x32_bf16(
                        av[m], bv[n], acc[m][n], 0, 0, 0);
            __builtin_amdgcn_s_setprio(0);
        }
        __syncthreads();
        cur ^= 1;
    }

    const int rq = lane >> 4;
    const bool has_br = (brow != nullptr), has_bc = (bcol != nullptr);
    #pragma unroll
    for (int m = 0; m < 4; ++m) {
        #pragma unroll
        for (int n = 0; n < 4; ++n) {
            const int gcol = bn*128 + wc + n*16 + r0;
            float cb = has_bc ? bcol[(long long)bcs*zh + gcol] : 0.f;
            #pragma unroll
            for (int j = 0; j < 4; ++j) {
                const int grow = bm*128 + wr + m*16 + rq*4 + j;
                float v = acc[m][n][j] + cb;
                if (has_br) v += brow[(long long)brs*zh + grow];
                const long long idx = coff + (long long)grow*ldc + gcol;
                if (OF32) ((float*)C)[idx] = v;
                else      ((unsigned short*)C)[idx] = f2bf(v);
            }
        }
    }
}

// Fused QKV projection. grid (3, S/128, NPAIR). A = Rd head-slice (lda=S),
// B = stacked [h][384][128] weights (Wq;Wk;Wv). bn=0/1 -> QK (pair,s,256);
// bn=2 -> Vt (pair,d,t) transposed scatter store.
__global__ __launch_bounds__(256, 2) void qkv_gemm(
    const unsigned short* __restrict__ Rd,
    const unsigned short* __restrict__ Wstk,
    const float* __restrict__ bstk,
    unsigned short* __restrict__ QK,
    unsigned short* __restrict__ Vt)
{
    __shared__ unsigned short As[2][128*64];
    __shared__ unsigned short Bs[2][128*64];
    const int gx = gridDim.x, gy = gridDim.y;
    const int nxy = gx * gy;
    const int nwg = nxy * gridDim.z;
    const int flat = (blockIdx.z*gy + blockIdx.y)*gx + blockIdx.x;
    const int id2 = (flat & 7)*(nwg >> 3) + (flat >> 3);
    const int z = id2 / nxy; const int r = id2 % nxy;
    const int bm = r / gx, bn = r % gx;
    const int h = z >> 1, nb = z & 1;          // pair = z
    const unsigned short* A = Rd + (long long)nb*S_LEN*S_LEN + h*128;
    const unsigned short* B = Wstk + (long long)h*384*128 + (long long)bn*128*128;
    const int tid = threadIdx.x, wid = tid >> 6, lane = tid & 63;
    const int l3 = lane >> 3;
    const int cg = (lane & 7) ^ l3;
    const unsigned short* Ag = A + (long long)(bm*128 + wid*32 + l3)*S_LEN + cg*8;
    const unsigned short* Bg = B + (long long)(wid*32 + l3)*HD + cg*8;

    f32x4 acc[4][4];
    #pragma unroll
    for (int m = 0; m < 4; ++m)
        #pragma unroll
        for (int n = 0; n < 4; ++n)
            #pragma unroll
            for (int j = 0; j < 4; ++j) acc[m][n][j] = 0.f;

    const int r0 = lane & 15, q = lane >> 4;
    const int wr = (wid >> 1) * 64, wc = (wid & 1) * 64;

    auto stage = [&](int buf, int kt) {
        unsigned short* as = &As[buf][wid*32*64];
        unsigned short* bs = &Bs[buf][wid*32*64];
        #pragma unroll
        for (int i = 0; i < 4; ++i) {
            gl_lds16(Ag + (long long)(i*8)*S_LEN + kt, as + i*8*64);
            gl_lds16(Bg + (long long)(i*8)*HD + kt, bs + i*8*64);
        }
    };

    stage(0, 0);
    __syncthreads();
    int cur = 0;
    #pragma unroll
    for (int t = 0; t < 2; ++t) {               // K = 128 = 2 tiles
        if (t == 0) stage(1, 64);
        #pragma unroll
        for (int ks = 0; ks < 2; ++ks) {
            bf16x8 av[4], bv[4];
            #pragma unroll
            for (int m = 0; m < 4; ++m) {
                const int ra = wr + m*16 + r0;
                av[m] = *(const bf16x8*)&As[cur][ra*64 + (((ks*4 + q) ^ (ra & 7)) << 3)];
                const int rb = wc + m*16 + r0;
                bv[m] = *(const bf16x8*)&Bs[cur][rb*64 + (((ks*4 + q) ^ (rb & 7)) << 3)];
            }
            __builtin_amdgcn_s_setprio(1);
            #pragma unroll
            for (int m = 0; m < 4; ++m)
                #pragma unroll
                for (int n = 0; n < 4; ++n)
                    acc[m][n] = __builtin_amdgcn_mfma_f32_16x16x32_bf16(
                        av[m], bv[n], acc[m][n], 0, 0, 0);
            __builtin_amdgcn_s_setprio(0);
        }
        __syncthreads();
        cur ^= 1;
    }

    const int rq = lane >> 4;
    #pragma unroll
    for (int m = 0; m < 4; ++m) {
        #pragma unroll
        for (int n = 0; n < 4; ++n) {
            const int lcol = wc + n*16 + r0;                    // 0..127
            const float cb = bstk[h*384 + bn*128 + lcol];
            #pragma unroll
            for (int j = 0; j < 4; ++j) {
                const int grow = bm*128 + wr + m*16 + rq*4 + j;
                const float v = acc[m][n][j] + cb;
                if (bn < 2)
                    QK[(long long)z*S_LEN*256 + (long long)grow*256 + bn*128 + lcol] = f2bf(v);
                else
                    Vt[(long long)z*HD*S_LEN + (long long)lcol*S_LEN + grow] = f2bf(v);
            }
        }
    }
}

// Fused flash attention, KVBLK=32, 40KB LDS -> 4 blocks/CU.
// grid (S/128, NPAIR), 256 thr, 4 waves x 32 q-rows.
__global__ __launch_bounds__(256, 4) void flash_attn(
    const unsigned short* __restrict__ QK,   // (pair, s, 256): Q 0-127 | K 128-255
    const unsigned short* __restrict__ Vt,   // (pair, d, t)
    unsigned short* __restrict__ O)          // (pair, s, d)
{
    __shared__ unsigned short Ks[2][32*128];   // 8KB x2, row=key (256B)
    __shared__ unsigned short Vs[2][128*32];   // 8KB x2, row=d (64B)
    __shared__ unsigned short Plds[4][32*32];  // 2KB per wave
    const int flat = blockIdx.y * gridDim.x + blockIdx.x;   // nwg = 512
    const int id2 = (flat & 7)*64 + (flat >> 3);            // XCD-chunked
    const int pair = id2 >> 4, qt = id2 & 15;
    const int tid = threadIdx.x, wid = tid >> 6, lane = tid & 63;
    const int r0 = lane & 15, q4 = lane >> 4;
    const long long qkbase = (long long)pair * S_LEN * 256;
    const unsigned short* Qp = QK + qkbase + (long long)(qt*128 + wid*32) * 256;
    const unsigned short* Kp = QK + qkbase + 128;
    const unsigned short* Vp = Vt + (long long)pair * HD * S_LEN;
    unsigned short* P = &Plds[wid][0];

    const int kr_l = lane >> 4;    // K staging: row within 4-row issue
    const int kc_l = lane & 15;    // 16B chunk within 256B row
    const int vr_l = lane >> 2;    // V staging: row within 16-row issue
    const int vc_l = lane & 3;     // 16B chunk within 64B row

    auto stageK = [&](int buf, int kv) {
        #pragma unroll
        for (int i = 0; i < 2; ++i) {
            const int srow = wid*8 + i*4 + kr_l;
            const int sc = kc_l ^ (srow & 7);
            gl_lds16(Kp + (long long)(kv + srow)*256 + sc*8,
                     &Ks[buf][(wid*8 + i*4)*128]);
        }
    };
    auto stageV = [&](int buf, int kv) {
        #pragma unroll
        for (int i = 0; i < 2; ++i) {
            const int srow = wid*32 + i*16 + vr_l;
            const int sc = vc_l ^ (srow & 3);
            gl_lds16(Vp + (long long)srow*S_LEN + kv + sc*8,
                     &Vs[buf][(wid*32 + i*16)*32]);
        }
    };

    bf16x8 qfr[2][4];
    #pragma unroll
    for (int qf = 0; qf < 2; ++qf)
        #pragma unroll
        for (int ks = 0; ks < 4; ++ks)
            qfr[qf][ks] = *(const bf16x8*)&Qp[(qf*16 + r0)*256 + ks*32 + q4*8];

    f32x4 o_acc[2][8];
    #pragma unroll
    for (int qf = 0; qf < 2; ++qf)
        #pragma unroll
        for (int nf = 0; nf < 8; ++nf)
            #pragma unroll
            for (int j = 0; j < 4; ++j) o_acc[qf][nf][j] = 0.f;
    float m_[2] = {-3.0e38f, -3.0e38f}, l_[2] = {0.f, 0.f};

    stageK(0, 0); stageV(0, 0);
    __syncthreads();
    int cur = 0;
    for (int kv = 0; kv < S_LEN; kv += 32) {
        if (kv + 32 < S_LEN) { stageK(cur ^ 1, kv + 32); stageV(cur ^ 1, kv + 32); }
        // ---- S^T: mfma(K, Q) -> row=key(kf*16+q4*4+j), col=query(r0) ----
        f32x4 sacc[2][2];
        #pragma unroll
        for (int kf = 0; kf < 2; ++kf)
            #pragma unroll
            for (int qf = 0; qf < 2; ++qf)
                #pragma unroll
                for (int j = 0; j < 4; ++j) sacc[kf][qf][j] = 0.f;
        #pragma unroll
        for (int ks = 0; ks < 4; ++ks) {
            bf16x8 kfr[2];
            #pragma unroll
            for (int kf = 0; kf < 2; ++kf) {
                const int row = kf*16 + r0;
                kfr[kf] = *(const bf16x8*)&Ks[cur][row*128 + (((ks*4 + q4) ^ (r0 & 7)) << 3)];
            }
            __builtin_amdgcn_s_setprio(1);
            #pragma unroll
            for (int kf = 0; kf < 2; ++kf)
                #pragma unroll
                for (int qf = 0; qf < 2; ++qf)
                    sacc[kf][qf] = __builtin_amdgcn_mfma_f32_16x16x32_bf16(
                        kfr[kf], qfr[qf][ks], sacc[kf][qf], 0, 0, 0);
            __builtin_amdgcn_s_setprio(0);
        }
        // ---- online softmax (lane's query col = qf*16 + r0) ----
        #pragma unroll
        for (int qf = 0; qf < 2; ++qf) {
            float t0 = fmaxf(fmaxf(sacc[0][qf][0], sacc[0][qf][1]),
                             fmaxf(sacc[0][qf][2], sacc[0][qf][3]));
            float t1 = fmaxf(fmaxf(sacc[1][qf][0], sacc[1][qf][1]),
                             fmaxf(sacc[1][qf][2], sacc[1][qf][3]));
            float tmax = fmaxf(t0, t1);
            tmax = fmaxf(tmax, __shfl_xor(tmax, 16));
            tmax = fmaxf(tmax, __shfl_xor(tmax, 32));
            if (__all(tmax <= m_[qf] + 8.f)) {
                float tsum = 0.f;
                #pragma unroll
                for (int kf = 0; kf < 2; ++kf)
                    #pragma unroll
                    for (int j = 0; j < 4; ++j) {
                        const float e = __expf(sacc[kf][qf][j] - m_[qf]);
                        sacc[kf][qf][j] = e; tsum += e;
                    }
                tsum += __shfl_xor(tsum, 16);
                tsum += __shfl_xor(tsum, 32);
                l_[qf] += tsum;
            } else {
                const float mnew = fmaxf(m_[qf], tmax);
                const float scale = __expf(m_[qf] - mnew);
                float tsum = 0.f;
                #pragma unroll
                for (int kf = 0; kf < 2; ++kf)
                    #pragma unroll
                    for (int j = 0; j < 4; ++j) {
                        const float e = __expf(sacc[kf][qf][j] - mnew);
                        sacc[kf][qf][j] = e; tsum += e;
                    }
                tsum += __shfl_xor(tsum, 16);
                tsum += __shfl_xor(tsum, 32);
                l_[qf] = l_[qf]*scale + tsum;
                m_[qf] = mnew;
                float sc[4];
                #pragma unroll
                for (int j = 0; j < 4; ++j) sc[j] = __shfl(scale, (q4*4 + j) | (lane & 48));
                #pragma unroll
                for (int nf = 0; nf < 8; ++nf)
                    #pragma unroll
                    for (int j = 0; j < 4; ++j) o_acc[qf][nf][j] *= sc[j];
            }
        }
        // ---- P -> per-wave LDS [32 rows][64B], XOR swizzle (row&3)<<4 ----
        #pragma unroll
        for (int qf = 0; qf < 2; ++qf)
            #pragma unroll
            for (int kf = 0; kf < 2; ++kf) {
                uint2 pk;
                pk.x = cvtpk(sacc[kf][qf][0], sacc[kf][qf][1]);
                pk.y = cvtpk(sacc[kf][qf][2], sacc[kf][qf][3]);
                const int row = qf*16 + r0;
                const int byte = row*64 + ((kf*32 + q4*8) ^ ((row & 3) << 4));
                *(uint2*)((char*)P + byte) = pk;
            }
        // ---- PV: O[q,d] += P[q,k] * Vt[d,k] ----
        {
            bf16x8 pa[2];
            #pragma unroll
            for (int qf = 0; qf < 2; ++qf) {
                const int row = qf*16 + r0;
                const int byte = row*64 + ((q4*16) ^ ((row & 3) << 4));
                pa[qf] = *(const bf16x8*)((char*)P + byte);
            }
            bf16x8 vb[8];
            #pragma unroll
            for (int nf = 0; nf < 8; ++nf) {
                const int row = nf*16 + r0;
                vb[nf] = *(const bf16x8*)&Vs[cur][row*32 + ((q4 ^ (r0 & 3)) << 3)];
            }
            __builtin_amdgcn_s_setprio(1);
            #pragma unroll
            for (int nf = 0; nf < 8; ++nf)
                #pragma unroll
                for (int qf = 0; qf < 2; ++qf)
                    o_acc[qf][nf] = __builtin_amdgcn_mfma_f32_16x16x32_bf16(
                        pa[qf], vb[nf], o_acc[qf][nf], 0, 0, 0);
            __builtin_amdgcn_s_setprio(0);
        }
        __syncthreads();
        cur ^= 1;
    }
    // ---- normalize + store ----
    const long long obase = (long long)pair * S_LEN * HD;
    #pragma unroll
    for (int qf = 0; qf < 2; ++qf) {
        const float inv = 1.f / l_[qf];
        float iv[4];
        #pragma unroll
        for (int j = 0; j < 4; ++j) iv[j] = __shfl(inv, (q4*4 + j) | (lane & 48));
        #pragma unroll
        for (int nf = 0; nf < 8; ++nf)
            #pragma unroll
            for (int j = 0; j < 4; ++j) {
                const int grow = qt*128 + wid*32 + qf*16 + q4*4 + j;
                O[obase + (long long)grow*HD + nf*16 + r0] = f2bf(o_acc[qf][nf][j] * iv[j]);
            }
    }
}

// x (NB,E,S) f32 -> xT (NB,S,E) bf16
__global__ __launch_bounds__(256) void transpose_conv(
    const float* __restrict__ x, unsigned short* __restrict__ xT)
{
    __shared__ float t[32][33];
    const int n = blockIdx.z;
    const int e0 = blockIdx.y * 32, s0 = blockIdx.x * 32;
    const int tx = threadIdx.x & 31, ty = threadIdx.x >> 5;
    #pragma unroll
    for (int i = 0; i < 4; ++i) {
        const int e = ty + i*8;
        t[e][tx] = x[((long long)n*E_DIM + e0 + e)*S_LEN + s0 + tx];
    }
    __syncthreads();
    #pragma unroll
    for (int i = 0; i < 4; ++i) {
        const int s = ty + i*8;
        xT[((long long)n*S_LEN + s0 + s)*E_DIM + e0 + tx] = f2bf(t[tx][s]);
    }
}

__global__ __launch_bounds__(256) void conv_bf16(
    const float* __restrict__ in, unsigned short* __restrict__ out, int n8)
{
    const int i = blockIdx.x * 256 + threadIdx.x;
    if (i >= n8) return;
    const float4 a = ((const float4*)in)[2*i];
    const float4 b = ((const float4*)in)[2*i + 1];
    unsigned short u[8] = {f2bf(a.x), f2bf(a.y), f2bf(a.z), f2bf(a.w),
                           f2bf(b.x), f2bf(b.y), f2bf(b.z), f2bf(b.w)};
    ((uint4*)out)[i] = *(const uint4*)u;
}

// Stack Wq/Wk/Wv -> Wstk[h][384][128] bf16 and biases -> bstk[h][384] f32
__global__ __launch_bounds__(256) void qkv_pack(
    const float* __restrict__ Wq, const float* __restrict__ Wk,
    const float* __restrict__ Wv, const float* __restrict__ bq,
    const float* __restrict__ bk, const float* __restrict__ bv,
    unsigned short* __restrict__ Wstk, float* __restrict__ bstk)
{
    const int i8 = blockIdx.x*256 + threadIdx.x;   // 98304 total
    const int per_h = 384*16;
    const int h = i8 / per_h, rem = i8 - h*per_h;
    const int rr = rem >> 4, c8 = rem & 15;
    const int rl = rr & 127;
    const float* src = (rr < 128) ? Wq : (rr < 256) ? Wk : Wv;
    const float* p = src + ((long long)h*128 + rl)*128 + c8*8;
    const float4 a = ((const float4*)p)[0];
    const float4 b = ((const float4*)p)[1];
    unsigned short u[8] = {f2bf(a.x), f2bf(a.y), f2bf(a.z), f2bf(a.w),
                           f2bf(b.x), f2bf(b.y), f2bf(b.z), f2bf(b.w)};
    ((uint4*)Wstk)[i8] = *(const uint4*)u;
    if (i8 < NH*384) {
        const int h2 = i8 / 384, r2 = i8 - h2*384;
        bstk[i8] = (r2 < 128) ? bq[h2*128 + r2]
                 : (r2 < 256) ? bk[h2*128 + r2 - 128]
                              : bv[h2*128 + r2 - 256];
    }
}

extern "C" void kernel_launch(void* const* d_in, const int* in_sizes, int n_in,
                              void* d_out, int out_size, void* d_ws, size_t ws_size,
                              hipStream_t stream)
{
    const float* x   = (const float*)d_in[0];
    const float* W_r = (const float*)d_in[1];
    const float* b_r = (const float*)d_in[2];
    const float* Wq  = (const float*)d_in[3];
    const float* bq  = (const float*)d_in[4];
    const float* Wk  = (const float*)d_in[5];
    const float* bk  = (const float*)d_in[6];
    const float* Wv  = (const float*)d_in[7];
    const float* bv  = (const float*)d_in[8];
    const float* Wo  = (const float*)d_in[9];
    const float* bo  = (const float*)d_in[10];
    float* out = (float*)d_out;
    (void)in_sizes; (void)n_in; (void)out_size; (void)ws_size;

    char* w = (char*)d_ws;
    size_t off = 0;
    auto take = [&](size_t bytes) -> unsigned short* {
        unsigned short* p = (unsigned short*)(w + off);
        off = (off + bytes + 255) & ~(size_t)255;
        return p;
    };
    unsigned short* Wr_b  = take((size_t)S_LEN*E_DIM*2);
    unsigned short* xT_b  = take((size_t)NB*S_LEN*E_DIM*2);
    unsigned short* Wstk  = take((size_t)NH*384*HD*2);
    float*          bstk  = (float*)take((size_t)NH*384*4);
    unsigned short* Wo_b  = take((size_t)E_DIM*S_LEN*2);
    unsigned short* Rd_b  = take((size_t)NB*S_LEN*S_LEN*2);   // reduced (n,j,s)
    unsigned short* QK_b  = take((size_t)NPAIR*S_LEN*256*2);  // (pair,s, Q|K)
    unsigned short* Vt_b  = take((size_t)NPAIR*HD*S_LEN*2);   // (pair,d,t)
    unsigned short* O_b   = take((size_t)NPAIR*S_LEN*HD*2);   // (pair,s,d)

    conv_bf16<<<dim3((S_LEN*E_DIM/8 + 255)/256), 256, 0, stream>>>(W_r, Wr_b, S_LEN*E_DIM/8);
    conv_bf16<<<dim3((E_DIM*S_LEN/8 + 255)/256), 256, 0, stream>>>(Wo, Wo_b, E_DIM*S_LEN/8);
    transpose_conv<<<dim3(S_LEN/32, E_DIM/32, NB), 256, 0, stream>>>(x, xT_b);
    qkv_pack<<<dim3(NH*384*16/256), 256, 0, stream>>>(Wq, Wk, Wv, bq, bk, bv, Wstk, bstk);

    // reduced[n,j,s] = W_r @ x[n]^T + b_r[j]
    gemm_bt<0,1><<<dim3(S_LEN/128, S_LEN/128, NB), 256, 0, stream>>>(
        Wr_b, xT_b, Rd_b, b_r, nullptr,
        E_DIM, E_DIM, E_DIM, S_LEN, 1,
        0LL, 0LL, (long long)S_LEN*E_DIM, 0LL, (long long)S_LEN*S_LEN, 0LL, 0, 0);

    // fused Q/K/V projections (one dispatch)
    qkv_gemm<<<dim3(3, S_LEN/128, NPAIR), 256, 0, stream>>>(Rd_b, Wstk, bstk, QK_b, Vt_b);

    // fused attention
    flash_attn<<<dim3(S_LEN/128, NPAIR), 256, 0, stream>>>(QK_b, Vt_b, O_b);

    // out[n] = O_resh[n] @ Wo^T + bo
    gemm_bt<1,1><<<dim3(E_DIM/128, S_LEN/128, NB), 256, 0, stream>>>(
        O_b, Wo_b, out, nullptr, bo,
        S_LEN, S_LEN, S_LEN, E_DIM, 1,
        (long long)S_LEN*S_LEN, 0LL, 0LL, 0LL, (long long)S_LEN*E_DIM, 0LL, 0, 0);
}